// Round 2
// baseline (2697.130 us; speedup 1.0000x reference)
//
#include <hip/hip_runtime.h>
#include <stdint.h>

typedef __bf16 bf16_t;
typedef bf16_t bf16x8 __attribute__((ext_vector_type(8)));
typedef float f32x4 __attribute__((ext_vector_type(4)));
typedef unsigned short us8 __attribute__((ext_vector_type(8)));
typedef unsigned short us4 __attribute__((ext_vector_type(4)));

#define B_ 4
#define T_ 4096
#define C_ 1024
#define D_ 128

#define NCHUNK_PB 288   // sum over j of ceil((j+1)/8) for j=0..63
#define L2E 1.4426950408889634f

__device__ __forceinline__ uint16_t f2bf(float f) {
    union { float f; uint32_t u; } v; v.f = f;
    uint32_t u = v.u;
    uint32_t r = (u + 0x7fffu + ((u >> 16) & 1u)) >> 16;
    return (uint16_t)r;
}

// ---------------------------------------------------------------------------
// Kernel 1: W[C,D] fp32 -> WT[w][n][k] bf16 (transposed), w in {q,k,v}
// ---------------------------------------------------------------------------
__global__ __launch_bounds__(256) void prep_w(const float* __restrict__ Wq,
                                              const float* __restrict__ Wk,
                                              const float* __restrict__ Wv,
                                              uint16_t* __restrict__ WT) {
    int idx = blockIdx.x * 256 + threadIdx.x;
    if (idx >= 3 * D_ * C_) return;
    int w   = idx / (D_ * C_);
    int rem = idx - w * (D_ * C_);
    int n   = rem / C_;
    int k   = rem - n * C_;
    const float* W = (w == 0) ? Wq : (w == 1) ? Wk : Wv;
    WT[idx] = f2bf(W[(size_t)k * D_ + n]);
}

// ---------------------------------------------------------------------------
// Kernel 2: fused QKV projection, 32-row tiles (grid 512 -> 2 blocks/CU),
// register-prefetch pipeline. Outputs qb/kb row-major bf16, vT transposed.
// ---------------------------------------------------------------------------
#define AST 40   // 32+8 elems: 80B stride, 2-way bank alias (free per m136)

__global__ __launch_bounds__(256) void qkv_gemm(const float* __restrict__ x,
                                                const uint16_t* __restrict__ WT,
                                                uint16_t* __restrict__ qb,
                                                uint16_t* __restrict__ kb,
                                                uint16_t* __restrict__ vT) {
    __shared__ __align__(16) uint16_t A_lds[32 * AST];
    __shared__ __align__(16) uint16_t W_lds[3][128 * AST];

    int tid  = threadIdx.x;
    int lane = tid & 63;
    int wave = tid >> 6;
    int quad = lane >> 4;
    int lx   = lane & 15;
    int wm   = wave >> 1, wn = wave & 1;
    int m0   = blockIdx.x * 32;

    f32x4 acc[3][4];
    for (int w = 0; w < 3; w++)
        for (int nf = 0; nf < 4; nf++)
            acc[w][nf] = (f32x4){0.f, 0.f, 0.f, 0.f};

    int arow = tid >> 3, acb = (tid & 7) * 4;  // A staging: 4 floats/thread

    float4 a_reg[2];
    us8    w_reg[2][6];

    auto ldG = [&](int k0, int pb) {
        a_reg[pb] = *(const float4*)(x + (size_t)(m0 + arow) * C_ + k0 + acb);
#pragma unroll
        for (int i = 0; i < 6; i++) {
            int f = i * 2048 + tid * 8;
            int w = f >> 12, n = (f >> 5) & 127, kk = f & 31;
            w_reg[pb][i] = *(const us8*)(WT + (size_t)w * (D_ * C_) + (size_t)n * C_ + k0 + kk);
        }
    };

    ldG(0, 0);
    for (int k0 = 0, it = 0; k0 < C_; k0 += 32, it++) {
        int pb = it & 1;
        __syncthreads();
        {
            float4 a = a_reg[pb];
            us4 u;
            u[0] = f2bf(a.x); u[1] = f2bf(a.y); u[2] = f2bf(a.z); u[3] = f2bf(a.w);
            *(us4*)&A_lds[arow * AST + acb] = u;
#pragma unroll
            for (int i = 0; i < 6; i++) {
                int f = i * 2048 + tid * 8;
                int w = f >> 12, n = (f >> 5) & 127, kk = f & 31;
                *(us8*)&W_lds[w][n * AST + kk] = w_reg[pb][i];
            }
        }
        if (k0 + 32 < C_) ldG(k0 + 32, pb ^ 1);
        __syncthreads();

        bf16x8 af = *(const bf16x8*)&A_lds[(wm * 16 + lx) * AST + quad * 8];
#pragma unroll
        for (int w = 0; w < 3; w++)
#pragma unroll
            for (int nf = 0; nf < 4; nf++) {
                bf16x8 bf = *(const bf16x8*)&W_lds[w][(wn * 64 + nf * 16 + lx) * AST + quad * 8];
                acc[w][nf] = __builtin_amdgcn_mfma_f32_16x16x32_bf16(af, bf, acc[w][nf], 0, 0, 0);
            }
    }

    // epilogue: C-layout row = quad*4+r, col = lx
    int mbase = m0 + wm * 16 + quad * 4;
#pragma unroll
    for (int nf = 0; nf < 4; nf++) {
        int n = wn * 64 + nf * 16 + lx;
#pragma unroll
        for (int r = 0; r < 4; r++)
            qb[(size_t)(mbase + r) * D_ + n] = f2bf(acc[0][nf][r]);
#pragma unroll
        for (int r = 0; r < 4; r++)
            kb[(size_t)(mbase + r) * D_ + n] = f2bf(acc[1][nf][r]);
        int batch = mbase >> 12;
        int t     = mbase & 4095;
        us4 pv;
        pv[0] = f2bf(acc[2][nf][0]);
        pv[1] = f2bf(acc[2][nf][1]);
        pv[2] = f2bf(acc[2][nf][2]);
        pv[3] = f2bf(acc[2][nf][3]);
        *(us4*)&vT[(size_t)batch * D_ * T_ + (size_t)n * T_ + t] = pv;
    }
}

// ---------------------------------------------------------------------------
// Kernel 3: split-K flash attention. Block = (batch, q-tile of 64, chunk of
// <=8 key-tiles). Writes unnormalized o + (m,l) partials.
// ---------------------------------------------------------------------------
#define KST 136  // 128+8
#define VST 72   // 64+8

__global__ __launch_bounds__(256) void attn(const uint16_t* __restrict__ qb,
                                            const uint16_t* __restrict__ kb,
                                            const uint16_t* __restrict__ vT,
                                            float* __restrict__ part,
                                            float* __restrict__ ml) {
    __shared__ __align__(16) uint16_t K_lds[64 * KST];
    __shared__ __align__(16) uint16_t V_lds[128 * VST];
    __shared__ __align__(16) uint16_t P_lds[4][16 * VST];

    int tid  = threadIdx.x;
    int lane = tid & 63;
    int wave = tid >> 6;
    int quad = lane >> 4;
    int lx   = lane & 15;

    // decode blockIdx -> (batch, jt, chunk)
    int gidx  = blockIdx.x;
    int batch = gidx / NCHUNK_PB;
    int L     = gidx - batch * NCHUNK_PB;
    int g = 0;
    while (g < 7 && 4 * (g + 1) * (g + 2) <= L) g++;
    int rem   = L - 4 * g * (g + 1);
    int jt    = 8 * g + rem / (g + 1);
    int chunk = rem - (rem / (g + 1)) * (g + 1);

    int q0     = jt * 64;
    int st0    = chunk * 8;
    int ntiles = min(8, jt - st0 + 1);

    const float scale = 0.08838834764831845f;  // 1/sqrt(128)

    bf16x8 qf[4];
    {
        const uint16_t* qp = qb + (size_t)(batch * T_ + q0 + wave * 16 + lx) * D_ + quad * 8;
#pragma unroll
        for (int kc = 0; kc < 4; kc++) qf[kc] = *(const bf16x8*)(qp + kc * 32);
    }

    f32x4 o[8];
    for (int i = 0; i < 8; i++) o[i] = (f32x4){0.f, 0.f, 0.f, 0.f};
    float m_i[4], l_i[4];
    for (int r = 0; r < 4; r++) { m_i[r] = -INFINITY; l_i[r] = 0.f; }

    int krow = tid >> 2, kcb = (tid & 3) * 32;
    int vd   = tid >> 1, vsb = (tid & 1) * 32;

    us8 kreg[2][4], vreg[2][4];
    auto ldG = [&](int st, int pb) {
        const uint16_t* kp = kb + (size_t)(batch * T_ + st * 64 + krow) * D_ + kcb;
#pragma unroll
        for (int i = 0; i < 4; i++) kreg[pb][i] = *(const us8*)(kp + i * 8);
        const uint16_t* vp = vT + (size_t)batch * D_ * T_ + (size_t)vd * T_ + st * 64 + vsb;
#pragma unroll
        for (int i = 0; i < 4; i++) vreg[pb][i] = *(const us8*)(vp + i * 8);
    };

    ldG(st0, 0);
    for (int it = 0; it < ntiles; it++) {
        int pb = it & 1;
        int s0 = (st0 + it) * 64;
        __syncthreads();
#pragma unroll
        for (int i = 0; i < 4; i++)
            *(us8*)&K_lds[krow * KST + kcb + i * 8] = kreg[pb][i];
#pragma unroll
        for (int i = 0; i < 4; i++)
            *(us8*)&V_lds[vd * VST + vsb + i * 8] = vreg[pb][i];
        if (it + 1 < ntiles) ldG(st0 + it + 1, pb ^ 1);
        __syncthreads();

        // S = Q K^T
        f32x4 s[4];
        for (int nf = 0; nf < 4; nf++) s[nf] = (f32x4){0.f, 0.f, 0.f, 0.f};
#pragma unroll
        for (int kc = 0; kc < 4; kc++)
#pragma unroll
            for (int nf = 0; nf < 4; nf++) {
                bf16x8 kf = *(const bf16x8*)&K_lds[(nf * 16 + lx) * KST + kc * 32 + quad * 8];
                s[nf] = __builtin_amdgcn_mfma_f32_16x16x32_bf16(qf[kc], kf, s[nf], 0, 0, 0);
            }

        int rowg = q0 + wave * 16 + quad * 4;
        float p[4][4];
        bool do_mask = (s0 + 63 > q0 + wave * 16);
#pragma unroll
        for (int nf = 0; nf < 4; nf++) {
            int colg = s0 + nf * 16 + lx;
#pragma unroll
            for (int r = 0; r < 4; r++) {
                float sv = s[nf][r] * scale;
                if (do_mask && (colg > rowg + r)) sv = -INFINITY;
                p[nf][r] = sv;
            }
        }

        float rm[4];
#pragma unroll
        for (int r = 0; r < 4; r++)
            rm[r] = fmaxf(fmaxf(p[0][r], p[1][r]), fmaxf(p[2][r], p[3][r]));
#pragma unroll
        for (int off = 1; off < 16; off <<= 1)
#pragma unroll
            for (int r = 0; r < 4; r++)
                rm[r] = fmaxf(rm[r], __shfl_xor(rm[r], off, 64));

        float alpha[4], rs[4];
#pragma unroll
        for (int r = 0; r < 4; r++) {
            float mn = fmaxf(m_i[r], rm[r]);
            alpha[r] = exp2f((m_i[r] - mn) * L2E);
            m_i[r]   = mn;
            float sum = 0.f;
#pragma unroll
            for (int nf = 0; nf < 4; nf++) {
                float e = exp2f((p[nf][r] - mn) * L2E);
                p[nf][r] = e;
                sum += e;
            }
            rs[r] = sum;
        }
#pragma unroll
        for (int off = 1; off < 16; off <<= 1)
#pragma unroll
            for (int r = 0; r < 4; r++)
                rs[r] += __shfl_xor(rs[r], off, 64);
#pragma unroll
        for (int r = 0; r < 4; r++) l_i[r] = l_i[r] * alpha[r] + rs[r];
#pragma unroll
        for (int i = 0; i < 8; i++)
#pragma unroll
            for (int r = 0; r < 4; r++) o[i][r] *= alpha[r];

        // P (C-layout) -> LDS -> A-layout (wave-private, no barrier needed)
#pragma unroll
        for (int nf = 0; nf < 4; nf++)
#pragma unroll
            for (int r = 0; r < 4; r++)
                P_lds[wave][(quad * 4 + r) * VST + nf * 16 + lx] = f2bf(p[nf][r]);

        bf16x8 pf[2];
        pf[0] = *(const bf16x8*)&P_lds[wave][lx * VST + quad * 8];
        pf[1] = *(const bf16x8*)&P_lds[wave][lx * VST + 32 + quad * 8];
#pragma unroll
        for (int nf = 0; nf < 8; nf++)
#pragma unroll
            for (int kc = 0; kc < 2; kc++) {
                bf16x8 vf = *(const bf16x8*)&V_lds[(nf * 16 + lx) * VST + kc * 32 + quad * 8];
                o[nf] = __builtin_amdgcn_mfma_f32_16x16x32_bf16(pf[kc], vf, o[nf], 0, 0, 0);
            }
    }

    // write unnormalized partial + (m,l)
    float* pp = part + (size_t)gidx * (64 * 128);
#pragma unroll
    for (int nf = 0; nf < 8; nf++)
#pragma unroll
        for (int r = 0; r < 4; r++) {
            int lrow = wave * 16 + quad * 4 + r;
            pp[lrow * 128 + nf * 16 + lx] = o[nf][r];
        }
    if (lx == 0) {
#pragma unroll
        for (int r = 0; r < 4; r++) {
            int lrow = wave * 16 + quad * 4 + r;
            ml[(size_t)gidx * 128 + lrow * 2]     = m_i[r];
            ml[(size_t)gidx * 128 + lrow * 2 + 1] = l_i[r];
        }
    }
}

// ---------------------------------------------------------------------------
// Kernel 4: combine split-K partials. Block = (batch, jt); 256 threads.
// ---------------------------------------------------------------------------
__global__ __launch_bounds__(256) void combine(const float* __restrict__ part,
                                               const float* __restrict__ ml,
                                               float* __restrict__ out) {
    int bidx  = blockIdx.x;
    int batch = bidx >> 6;
    int jt    = bidx & 63;
    int g     = jt >> 3;
    int base  = batch * NCHUNK_PB + jt + g * (jt - 4 * g - 4);
    int nch   = g + 1;

    int tid  = threadIdx.x;
    int lrow = tid >> 2;
    int c0   = (tid & 3) * 32;

    float M = -INFINITY;
    for (int c = 0; c < nch; c++)
        M = fmaxf(M, ml[(size_t)(base + c) * 128 + lrow * 2]);

    float Lsum = 0.f;
    f32x4 acc[8];
#pragma unroll
    for (int i = 0; i < 8; i++) acc[i] = (f32x4){0.f, 0.f, 0.f, 0.f};

    for (int c = 0; c < nch; c++) {
        float m = ml[(size_t)(base + c) * 128 + lrow * 2];
        float l = ml[(size_t)(base + c) * 128 + lrow * 2 + 1];
        float w = exp2f((m - M) * L2E);
        Lsum += l * w;
        const float* p = part + (size_t)(base + c) * (64 * 128) + lrow * 128 + c0;
#pragma unroll
        for (int i = 0; i < 8; i++) {
            f32x4 v = *(const f32x4*)(p + i * 4);
            acc[i] += v * w;
        }
    }
    float inv = 1.f / Lsum;
    size_t row = (size_t)(batch * T_ + jt * 64 + lrow);
#pragma unroll
    for (int i = 0; i < 8; i++)
        *(f32x4*)(out + row * 128 + c0 + i * 4) = acc[i] * inv;
}

// ---------------------------------------------------------------------------
extern "C" void kernel_launch(void* const* d_in, const int* in_sizes, int n_in,
                              void* d_out, int out_size, void* d_ws, size_t ws_size,
                              hipStream_t stream) {
    const float* x  = (const float*)d_in[0];
    const float* Wq = (const float*)d_in[1];
    const float* Wk = (const float*)d_in[2];
    const float* Wv = (const float*)d_in[3];
    float* out = (float*)d_out;

    uint16_t* ws = (uint16_t*)d_ws;
    uint16_t* qb = ws;                                   // 16384*128 bf16
    uint16_t* kb = qb + (size_t)16384 * 128;
    uint16_t* vT = kb + (size_t)16384 * 128;
    uint16_t* WT = vT + (size_t)16384 * 128;             // 3*128*1024
    float* part = (float*)(WT + (size_t)3 * D_ * C_);    // 1152*64*128 fp32
    float* ml   = part + (size_t)4 * NCHUNK_PB * 64 * 128;  // 1152*64*2 fp32

    prep_w<<<dim3((3 * D_ * C_ + 255) / 256), dim3(256), 0, stream>>>(Wq, Wk, Wv, WT);
    qkv_gemm<<<dim3(16384 / 32), dim3(256), 0, stream>>>(x, WT, qb, kb, vT);
    attn<<<dim3(B_ * NCHUNK_PB), dim3(256), 0, stream>>>(qb, kb, vT, part, ml);
    combine<<<dim3(B_ * (T_ / 64)), dim3(256), 0, stream>>>(part, ml, out);
}

// Round 3
// 219.456 us; speedup vs baseline: 12.2901x; 12.2901x over previous
//
#include <hip/hip_runtime.h>
#include <stdint.h>

typedef __bf16 bf16_t;
typedef bf16_t bf16x8 __attribute__((ext_vector_type(8)));
typedef float f32x4 __attribute__((ext_vector_type(4)));
typedef unsigned short us8 __attribute__((ext_vector_type(8)));
typedef unsigned short us4 __attribute__((ext_vector_type(4)));

#define B_ 4
#define T_ 4096
#define C_ 1024
#define D_ 128

#define NCHUNK_PB 288   // sum over j of ceil((j+1)/8) for j=0..63
#define L2E 1.4426950408889634f

__device__ __forceinline__ uint16_t f2bf(float f) {
    union { float f; uint32_t u; } v; v.f = f;
    uint32_t u = v.u;
    uint32_t r = (u + 0x7fffu + ((u >> 16) & 1u)) >> 16;
    return (uint16_t)r;
}

// ---------------------------------------------------------------------------
// Kernel 1: W[C,D] fp32 -> WT[w][n][k] bf16 (transposed), w in {q,k,v}
// ---------------------------------------------------------------------------
__global__ __launch_bounds__(256) void prep_w(const float* __restrict__ Wq,
                                              const float* __restrict__ Wk,
                                              const float* __restrict__ Wv,
                                              uint16_t* __restrict__ WT) {
    int idx = blockIdx.x * 256 + threadIdx.x;
    if (idx >= 3 * D_ * C_) return;
    int w   = idx / (D_ * C_);
    int rem = idx - w * (D_ * C_);
    int n   = rem / C_;
    int k   = rem - n * C_;
    const float* W = (w == 0) ? Wq : (w == 1) ? Wk : Wv;
    WT[idx] = f2bf(W[(size_t)k * D_ + n]);
}

// ---------------------------------------------------------------------------
// Kernel 2: fused QKV projection, 32-row tiles (512 blocks, 4 blocks/CU).
// Simple sync-load-sync loop; NO runtime-indexed register arrays.
// ---------------------------------------------------------------------------
#define AST 40   // 32+8 elems: 80B stride, 2-way bank alias (free per m136)

__global__ __launch_bounds__(256) void qkv_gemm(const float* __restrict__ x,
                                                const uint16_t* __restrict__ WT,
                                                uint16_t* __restrict__ qb,
                                                uint16_t* __restrict__ kb,
                                                uint16_t* __restrict__ vT) {
    __shared__ __align__(16) uint16_t A_lds[32 * AST];
    __shared__ __align__(16) uint16_t W_lds[3][128 * AST];

    int tid  = threadIdx.x;
    int lane = tid & 63;
    int wave = tid >> 6;
    int quad = lane >> 4;
    int lx   = lane & 15;
    int wm   = wave >> 1, wn = wave & 1;
    int m0   = blockIdx.x * 32;

    f32x4 acc[3][4];
    for (int w = 0; w < 3; w++)
        for (int nf = 0; nf < 4; nf++)
            acc[w][nf] = (f32x4){0.f, 0.f, 0.f, 0.f};

    int arow = tid >> 3, acb = (tid & 7) * 4;  // A staging: 4 floats/thread

    for (int k0 = 0; k0 < C_; k0 += 32) {
        // stage A (fp32 -> bf16), 32x32
        {
            float4 a = *(const float4*)(x + (size_t)(m0 + arow) * C_ + k0 + acb);
            us4 u;
            u[0] = f2bf(a.x); u[1] = f2bf(a.y); u[2] = f2bf(a.z); u[3] = f2bf(a.w);
            *(us4*)&A_lds[arow * AST + acb] = u;
        }
        // stage 3 W tiles: 3*128*32 elems = 6 us8 per thread
#pragma unroll
        for (int i = 0; i < 6; i++) {
            int f = i * 2048 + tid * 8;
            int w = f >> 12, n = (f >> 5) & 127, kk = f & 31;
            *(us8*)&W_lds[w][n * AST + kk] =
                *(const us8*)(WT + (size_t)w * (D_ * C_) + (size_t)n * C_ + k0 + kk);
        }
        __syncthreads();

        bf16x8 af = *(const bf16x8*)&A_lds[(wm * 16 + lx) * AST + quad * 8];
#pragma unroll
        for (int w = 0; w < 3; w++)
#pragma unroll
            for (int nf = 0; nf < 4; nf++) {
                bf16x8 bf = *(const bf16x8*)&W_lds[w][(wn * 64 + nf * 16 + lx) * AST + quad * 8];
                acc[w][nf] = __builtin_amdgcn_mfma_f32_16x16x32_bf16(af, bf, acc[w][nf], 0, 0, 0);
            }
        __syncthreads();
    }

    // epilogue: C-layout row = quad*4+r, col = lx
    int mbase = m0 + wm * 16 + quad * 4;
#pragma unroll
    for (int nf = 0; nf < 4; nf++) {
        int n = wn * 64 + nf * 16 + lx;
#pragma unroll
        for (int r = 0; r < 4; r++)
            qb[(size_t)(mbase + r) * D_ + n] = f2bf(acc[0][nf][r]);
#pragma unroll
        for (int r = 0; r < 4; r++)
            kb[(size_t)(mbase + r) * D_ + n] = f2bf(acc[1][nf][r]);
        int batch = mbase >> 12;
        int t     = mbase & 4095;
        us4 pv;
        pv[0] = f2bf(acc[2][nf][0]);
        pv[1] = f2bf(acc[2][nf][1]);
        pv[2] = f2bf(acc[2][nf][2]);
        pv[3] = f2bf(acc[2][nf][3]);
        *(us4*)&vT[(size_t)batch * D_ * T_ + (size_t)n * T_ + t] = pv;
    }
}

// ---------------------------------------------------------------------------
// Kernel 3: split-K flash attention. Block = (batch, q-tile of 64, chunk of
// <=8 key-tiles). R1-style staging (no reg-array pipeline). Longest-first.
// ---------------------------------------------------------------------------
#define KST 136  // 128+8
#define VST 72   // 64+8

__global__ __launch_bounds__(256) void attn(const uint16_t* __restrict__ qb,
                                            const uint16_t* __restrict__ kb,
                                            const uint16_t* __restrict__ vT,
                                            float* __restrict__ part,
                                            float* __restrict__ ml) {
    __shared__ __align__(16) uint16_t K_lds[64 * KST];
    __shared__ __align__(16) uint16_t V_lds[128 * VST];
    __shared__ __align__(16) uint16_t P_lds[4][16 * VST];

    int tid  = threadIdx.x;
    int lane = tid & 63;
    int wave = tid >> 6;
    int quad = lane >> 4;
    int lx   = lane & 15;

    // decode blockIdx -> (batch, logical chunk L), longest chunks first
    int batch = blockIdx.x & 3;
    int L     = NCHUNK_PB - 1 - (blockIdx.x >> 2);
    int g = 0;
    while (g < 7 && 4 * (g + 1) * (g + 2) <= L) g++;
    int rem   = L - 4 * g * (g + 1);
    int jt    = 8 * g + rem / (g + 1);
    int chunk = rem - (rem / (g + 1)) * (g + 1);
    int lidx  = batch * NCHUNK_PB + L;   // partial-buffer index (logical)

    int q0     = jt * 64;
    int st0    = chunk * 8;
    int ntiles = min(8, jt - st0 + 1);

    const float scale = 0.08838834764831845f;  // 1/sqrt(128)

    bf16x8 qf[4];
    {
        const uint16_t* qp = qb + (size_t)(batch * T_ + q0 + wave * 16 + lx) * D_ + quad * 8;
#pragma unroll
        for (int kc = 0; kc < 4; kc++) qf[kc] = *(const bf16x8*)(qp + kc * 32);
    }

    f32x4 o[8];
    for (int i = 0; i < 8; i++) o[i] = (f32x4){0.f, 0.f, 0.f, 0.f};
    float m_i[4], l_i[4];
    for (int r = 0; r < 4; r++) { m_i[r] = -INFINITY; l_i[r] = 0.f; }

    int krow = tid >> 2, kcb = (tid & 3) * 32;
    int vd   = tid >> 1, vsb = (tid & 1) * 32;

    for (int it = 0; it < ntiles; it++) {
        int s0 = (st0 + it) * 64;
        // stage K tile [64 keys][128 d]
        {
            const uint16_t* kp = kb + (size_t)(batch * T_ + s0 + krow) * D_ + kcb;
#pragma unroll
            for (int i = 0; i < 4; i++)
                *(us8*)&K_lds[krow * KST + kcb + i * 8] = *(const us8*)(kp + i * 8);
        }
        // stage V^T tile [128 d][64 keys]
        {
            const uint16_t* vp = vT + (size_t)batch * D_ * T_ + (size_t)vd * T_ + s0 + vsb;
#pragma unroll
            for (int i = 0; i < 4; i++)
                *(us8*)&V_lds[vd * VST + vsb + i * 8] = *(const us8*)(vp + i * 8);
        }
        __syncthreads();

        // S = Q K^T
        f32x4 s[4];
        for (int nf = 0; nf < 4; nf++) s[nf] = (f32x4){0.f, 0.f, 0.f, 0.f};
#pragma unroll
        for (int kc = 0; kc < 4; kc++)
#pragma unroll
            for (int nf = 0; nf < 4; nf++) {
                bf16x8 kf = *(const bf16x8*)&K_lds[(nf * 16 + lx) * KST + kc * 32 + quad * 8];
                s[nf] = __builtin_amdgcn_mfma_f32_16x16x32_bf16(qf[kc], kf, s[nf], 0, 0, 0);
            }

        int rowg = q0 + wave * 16 + quad * 4;
        float p[4][4];
        bool do_mask = (s0 + 63 > q0 + wave * 16);
#pragma unroll
        for (int nf = 0; nf < 4; nf++) {
            int colg = s0 + nf * 16 + lx;
#pragma unroll
            for (int r = 0; r < 4; r++) {
                float sv = s[nf][r] * scale;
                if (do_mask && (colg > rowg + r)) sv = -INFINITY;
                p[nf][r] = sv;
            }
        }

        float rm[4];
#pragma unroll
        for (int r = 0; r < 4; r++)
            rm[r] = fmaxf(fmaxf(p[0][r], p[1][r]), fmaxf(p[2][r], p[3][r]));
#pragma unroll
        for (int off = 1; off < 16; off <<= 1)
#pragma unroll
            for (int r = 0; r < 4; r++)
                rm[r] = fmaxf(rm[r], __shfl_xor(rm[r], off, 64));

        float alpha[4], rs[4];
#pragma unroll
        for (int r = 0; r < 4; r++) {
            float mn = fmaxf(m_i[r], rm[r]);
            alpha[r] = exp2f((m_i[r] - mn) * L2E);
            m_i[r]   = mn;
            float sum = 0.f;
#pragma unroll
            for (int nf = 0; nf < 4; nf++) {
                float e = exp2f((p[nf][r] - mn) * L2E);
                p[nf][r] = e;
                sum += e;
            }
            rs[r] = sum;
        }
#pragma unroll
        for (int off = 1; off < 16; off <<= 1)
#pragma unroll
            for (int r = 0; r < 4; r++)
                rs[r] += __shfl_xor(rs[r], off, 64);
#pragma unroll
        for (int r = 0; r < 4; r++) l_i[r] = l_i[r] * alpha[r] + rs[r];
#pragma unroll
        for (int i = 0; i < 8; i++)
#pragma unroll
            for (int r = 0; r < 4; r++) o[i][r] *= alpha[r];

        // P (C-layout) -> LDS -> A-layout (wave-private region)
#pragma unroll
        for (int nf = 0; nf < 4; nf++)
#pragma unroll
            for (int r = 0; r < 4; r++)
                P_lds[wave][(quad * 4 + r) * VST + nf * 16 + lx] = f2bf(p[nf][r]);

        bf16x8 pf[2];
        pf[0] = *(const bf16x8*)&P_lds[wave][lx * VST + quad * 8];
        pf[1] = *(const bf16x8*)&P_lds[wave][lx * VST + 32 + quad * 8];
#pragma unroll
        for (int nf = 0; nf < 8; nf++)
#pragma unroll
            for (int kc = 0; kc < 2; kc++) {
                bf16x8 vf = *(const bf16x8*)&V_lds[(nf * 16 + lx) * VST + kc * 32 + quad * 8];
                o[nf] = __builtin_amdgcn_mfma_f32_16x16x32_bf16(pf[kc], vf, o[nf], 0, 0, 0);
            }
        __syncthreads();
    }

    // write unnormalized partial + (m,l) at the LOGICAL index
    float* pp = part + (size_t)lidx * (64 * 128);
#pragma unroll
    for (int nf = 0; nf < 8; nf++)
#pragma unroll
        for (int r = 0; r < 4; r++) {
            int lrow = wave * 16 + quad * 4 + r;
            pp[lrow * 128 + nf * 16 + lx] = o[nf][r];
        }
    if (lx == 0) {
#pragma unroll
        for (int r = 0; r < 4; r++) {
            int lrow = wave * 16 + quad * 4 + r;
            ml[(size_t)lidx * 128 + lrow * 2]     = m_i[r];
            ml[(size_t)lidx * 128 + lrow * 2 + 1] = l_i[r];
        }
    }
}

// ---------------------------------------------------------------------------
// Kernel 4: combine split-K partials. Block = (batch, jt); 256 threads.
// ---------------------------------------------------------------------------
__global__ __launch_bounds__(256) void combine(const float* __restrict__ part,
                                               const float* __restrict__ ml,
                                               float* __restrict__ out) {
    int bidx  = blockIdx.x;
    int batch = bidx >> 6;
    int jt    = bidx & 63;
    int g     = jt >> 3;
    int base  = batch * NCHUNK_PB + jt + g * (jt - 4 * g - 4);  // (g+1)(jt-4g) offset
    int nch   = g + 1;

    int tid  = threadIdx.x;
    int lrow = tid >> 2;
    int c0   = (tid & 3) * 32;

    float M = -INFINITY;
    for (int c = 0; c < nch; c++)
        M = fmaxf(M, ml[(size_t)(base + c) * 128 + lrow * 2]);

    float Lsum = 0.f;
    f32x4 acc[8];
#pragma unroll
    for (int i = 0; i < 8; i++) acc[i] = (f32x4){0.f, 0.f, 0.f, 0.f};

    for (int c = 0; c < nch; c++) {
        float m = ml[(size_t)(base + c) * 128 + lrow * 2];
        float l = ml[(size_t)(base + c) * 128 + lrow * 2 + 1];
        float w = exp2f((m - M) * L2E);
        Lsum += l * w;
        const float* p = part + (size_t)(base + c) * (64 * 128) + lrow * 128 + c0;
#pragma unroll
        for (int i = 0; i < 8; i++) {
            f32x4 v = *(const f32x4*)(p + i * 4);
            acc[i] += v * w;
        }
    }
    float inv = 1.f / Lsum;
    size_t row = (size_t)(batch * T_ + jt * 64 + lrow);
#pragma unroll
    for (int i = 0; i < 8; i++)
        *(f32x4*)(out + row * 128 + c0 + i * 4) = acc[i] * inv;
}

// ---------------------------------------------------------------------------
extern "C" void kernel_launch(void* const* d_in, const int* in_sizes, int n_in,
                              void* d_out, int out_size, void* d_ws, size_t ws_size,
                              hipStream_t stream) {
    const float* x  = (const float*)d_in[0];
    const float* Wq = (const float*)d_in[1];
    const float* Wk = (const float*)d_in[2];
    const float* Wv = (const float*)d_in[3];
    float* out = (float*)d_out;

    uint16_t* ws = (uint16_t*)d_ws;
    uint16_t* qb = ws;                                   // 16384*128 bf16
    uint16_t* kb = qb + (size_t)16384 * 128;
    uint16_t* vT = kb + (size_t)16384 * 128;
    uint16_t* WT = vT + (size_t)16384 * 128;             // 3*128*1024
    float* part = (float*)(WT + (size_t)3 * D_ * C_);    // 1152*64*128 fp32
    float* ml   = part + (size_t)4 * NCHUNK_PB * 64 * 128;  // 1152*64*2 fp32

    prep_w<<<dim3((3 * D_ * C_ + 255) / 256), dim3(256), 0, stream>>>(Wq, Wk, Wv, WT);
    qkv_gemm<<<dim3(16384 / 32), dim3(256), 0, stream>>>(x, WT, qb, kb, vT);
    attn<<<dim3(B_ * NCHUNK_PB), dim3(256), 0, stream>>>(qb, kb, vT, part, ml);
    combine<<<dim3(B_ * (T_ / 64)), dim3(256), 0, stream>>>(part, ml, out);
}

// Round 4
// 210.770 us; speedup vs baseline: 12.7966x; 1.0412x over previous
//
#include <hip/hip_runtime.h>
#include <stdint.h>

typedef __bf16 bf16_t;
typedef bf16_t bf16x8 __attribute__((ext_vector_type(8)));
typedef float f32x4 __attribute__((ext_vector_type(4)));
typedef unsigned short us8 __attribute__((ext_vector_type(8)));
typedef unsigned short us4 __attribute__((ext_vector_type(4)));
typedef unsigned int u32x4 __attribute__((ext_vector_type(4)));

#define B_ 4
#define T_ 4096
#define C_ 1024
#define D_ 128

#define NCHUNK_PB 288   // sum over j of ceil((j+1)/8) for j=0..63
#define QSCALE 0.12751744f  // (1/sqrt(128)) * log2(e), folded into Q

__device__ __forceinline__ uint16_t f2bf(float f) {
    union { float f; uint32_t u; } v; v.f = f;
    uint32_t u = v.u;
    uint32_t r = (u + 0x7fffu + ((u >> 16) & 1u)) >> 16;
    return (uint16_t)r;
}

// round-half-up bf16 (2 VALU); bias ~2^-9 ulp, well inside error budget
__device__ __forceinline__ uint16_t bfru(float f) {
    return (uint16_t)((__float_as_uint(f) + 0x8000u) >> 16);
}

// ---------------------------------------------------------------------------
// Kernel 1: W[C,D] fp32 -> WT[w][n][k] bf16 (transposed), w in {q,k,v}
// ---------------------------------------------------------------------------
__global__ __launch_bounds__(256) void prep_w(const float* __restrict__ Wq,
                                              const float* __restrict__ Wk,
                                              const float* __restrict__ Wv,
                                              uint16_t* __restrict__ WT) {
    int idx = blockIdx.x * 256 + threadIdx.x;
    if (idx >= 3 * D_ * C_) return;
    int w   = idx / (D_ * C_);
    int rem = idx - w * (D_ * C_);
    int n   = rem / C_;
    int k   = rem - n * C_;
    const float* W = (w == 0) ? Wq : (w == 1) ? Wk : Wv;
    WT[idx] = f2bf(W[(size_t)k * D_ + n]);
}

// ---------------------------------------------------------------------------
// Kernel 2: QKV projection, per-W blocking: grid = 3 W x 256 M-tiles(64 rows)
// = 768 blocks (3/CU). BK=64, 16 iterations. Q gets QSCALE folded in.
// ---------------------------------------------------------------------------
#define GST 72   // 64+8 elems leading-dim pad

__global__ __launch_bounds__(256) void qkv_gemm(const float* __restrict__ x,
                                                const uint16_t* __restrict__ WT,
                                                uint16_t* __restrict__ qb,
                                                uint16_t* __restrict__ kb,
                                                uint16_t* __restrict__ vT) {
    __shared__ __align__(16) uint16_t A_lds[64 * GST];
    __shared__ __align__(16) uint16_t W_lds[128 * GST];

    int tid  = threadIdx.x;
    int lane = tid & 63;
    int wave = tid >> 6;
    int quad = lane >> 4;
    int lx   = lane & 15;
    int wm   = wave >> 1, wn = wave & 1;

    int bx   = blockIdx.x;
    int wsel = bx % 3;
    int m0   = (bx / 3) * 64;
    const uint16_t* Wp = WT + (size_t)wsel * (D_ * C_);

    f32x4 acc[2][4];
    for (int mf = 0; mf < 2; mf++)
        for (int nf = 0; nf < 4; nf++)
            acc[mf][nf] = (f32x4){0.f, 0.f, 0.f, 0.f};

    int arow = tid >> 2, acb = (tid & 3) * 16;  // A: 16 floats/thread
    int wrow = tid >> 1, wcb = (tid & 1) * 32;  // W: 32 bf16/thread

    for (int k0 = 0; k0 < C_; k0 += 64) {
        // stage A (fp32 -> bf16 packed via v_perm)
        {
            const float* xp = x + (size_t)(m0 + arow) * C_ + k0 + acb;
            uint32_t d[8];
#pragma unroll
            for (int j = 0; j < 4; j++) {
                float4 f = *(const float4*)(xp + j * 4);
                uint32_t u0 = __float_as_uint(f.x) + 0x8000u;
                uint32_t u1 = __float_as_uint(f.y) + 0x8000u;
                uint32_t u2 = __float_as_uint(f.z) + 0x8000u;
                uint32_t u3 = __float_as_uint(f.w) + 0x8000u;
                d[2 * j]     = __builtin_amdgcn_perm(u1, u0, 0x07060302);
                d[2 * j + 1] = __builtin_amdgcn_perm(u3, u2, 0x07060302);
            }
            *(u32x4*)&A_lds[arow * GST + acb]     = (u32x4){d[0], d[1], d[2], d[3]};
            *(u32x4*)&A_lds[arow * GST + acb + 8] = (u32x4){d[4], d[5], d[6], d[7]};
        }
        // stage W slice (bf16, transposed already)
        {
            const uint16_t* wp = Wp + (size_t)wrow * C_ + k0 + wcb;
#pragma unroll
            for (int i = 0; i < 4; i++)
                *(us8*)&W_lds[wrow * GST + wcb + i * 8] = *(const us8*)(wp + i * 8);
        }
        __syncthreads();

#pragma unroll
        for (int kc = 0; kc < 2; kc++) {
            bf16x8 af[2];
#pragma unroll
            for (int mf = 0; mf < 2; mf++)
                af[mf] = *(const bf16x8*)&A_lds[(wm * 32 + mf * 16 + lx) * GST + kc * 32 + quad * 8];
#pragma unroll
            for (int nf = 0; nf < 4; nf++) {
                bf16x8 bf = *(const bf16x8*)&W_lds[(wn * 64 + nf * 16 + lx) * GST + kc * 32 + quad * 8];
                acc[0][nf] = __builtin_amdgcn_mfma_f32_16x16x32_bf16(af[0], bf, acc[0][nf], 0, 0, 0);
                acc[1][nf] = __builtin_amdgcn_mfma_f32_16x16x32_bf16(af[1], bf, acc[1][nf], 0, 0, 0);
            }
        }
        __syncthreads();
    }

    // epilogue: C-layout row = quad*4+r, col = lx
    int mrow0 = m0 + wm * 32 + quad * 4;
    if (wsel == 2) {
#pragma unroll
        for (int mf = 0; mf < 2; mf++) {
            int mbase = mrow0 + mf * 16;
            int batch = mbase >> 12;
            int t     = mbase & 4095;
#pragma unroll
            for (int nf = 0; nf < 4; nf++) {
                int n = wn * 64 + nf * 16 + lx;
                us4 pv;
#pragma unroll
                for (int r = 0; r < 4; r++) pv[r] = bfru(acc[mf][nf][r]);
                *(us4*)&vT[(size_t)batch * D_ * T_ + (size_t)n * T_ + t] = pv;
            }
        }
    } else {
        uint16_t* dst = (wsel == 0) ? qb : kb;
        float sc = (wsel == 0) ? QSCALE : 1.0f;
#pragma unroll
        for (int mf = 0; mf < 2; mf++)
#pragma unroll
            for (int nf = 0; nf < 4; nf++) {
                int n = wn * 64 + nf * 16 + lx;
#pragma unroll
                for (int r = 0; r < 4; r++)
                    dst[(size_t)(mrow0 + mf * 16 + r) * D_ + n] = bfru(acc[mf][nf][r] * sc);
            }
    }
}

// ---------------------------------------------------------------------------
// Kernel 3: split-K flash attention. V_lds has a ones-row (row 128) so the
// softmax denominator l falls out of a 9th PV accumulator fragment.
// Scores arrive pre-scaled by QSCALE (log2 domain): exp2 directly.
// ---------------------------------------------------------------------------
#define KST 136  // 128+8
#define VST 72   // 64+8

__global__ __launch_bounds__(256) void attn(const uint16_t* __restrict__ qb,
                                            const uint16_t* __restrict__ kb,
                                            const uint16_t* __restrict__ vT,
                                            float* __restrict__ part,
                                            float* __restrict__ ml) {
    __shared__ __align__(16) uint16_t K_lds[64 * KST];
    __shared__ __align__(16) uint16_t V_lds[144 * VST];  // rows 128..143: ones row + zeros
    __shared__ __align__(16) uint16_t P_lds[4][16 * VST];

    int tid  = threadIdx.x;
    int lane = tid & 63;
    int wave = tid >> 6;
    int quad = lane >> 4;
    int lx   = lane & 15;

    // decode blockIdx -> (batch, logical chunk L), longest chunks first
    int batch = blockIdx.x & 3;
    int L     = NCHUNK_PB - 1 - (blockIdx.x >> 2);
    int g = 0;
    while (g < 7 && 4 * (g + 1) * (g + 2) <= L) g++;
    int rem   = L - 4 * g * (g + 1);
    int jt    = 8 * g + rem / (g + 1);
    int chunk = rem - (rem / (g + 1)) * (g + 1);
    int lidx  = batch * NCHUNK_PB + L;

    int q0     = jt * 64;
    int st0    = chunk * 8;
    int ntiles = min(8, jt - st0 + 1);

    // init V_lds rows 128..143: row 128 = 1.0 (bf16 0x3F80), rest 0
    for (int i = tid; i < 16 * VST; i += 256) {
        int r = i / VST;
        V_lds[(128 + r) * VST + (i - r * VST)] = (r == 0) ? 0x3F80 : 0;
    }

    bf16x8 qf[4];
    {
        const uint16_t* qp = qb + (size_t)(batch * T_ + q0 + wave * 16 + lx) * D_ + quad * 8;
#pragma unroll
        for (int kc = 0; kc < 4; kc++) qf[kc] = *(const bf16x8*)(qp + kc * 32);
    }

    f32x4 o[9];  // o[8] col 0 = running denominator l
    for (int i = 0; i < 9; i++) o[i] = (f32x4){0.f, 0.f, 0.f, 0.f};
    float m_i[4];
    for (int r = 0; r < 4; r++) m_i[r] = -INFINITY;

    int krow = tid >> 2, kcb = (tid & 3) * 32;
    int vd   = tid >> 1, vsb = (tid & 1) * 32;

    for (int it = 0; it < ntiles; it++) {
        int s0 = (st0 + it) * 64;
        {
            const uint16_t* kp = kb + (size_t)(batch * T_ + s0 + krow) * D_ + kcb;
#pragma unroll
            for (int i = 0; i < 4; i++)
                *(us8*)&K_lds[krow * KST + kcb + i * 8] = *(const us8*)(kp + i * 8);
        }
        {
            const uint16_t* vp = vT + (size_t)batch * D_ * T_ + (size_t)vd * T_ + s0 + vsb;
#pragma unroll
            for (int i = 0; i < 4; i++)
                *(us8*)&V_lds[vd * VST + vsb + i * 8] = *(const us8*)(vp + i * 8);
        }
        __syncthreads();

        // S = Q K^T (pre-scaled, log2 domain)
        f32x4 s[4];
        for (int nf = 0; nf < 4; nf++) s[nf] = (f32x4){0.f, 0.f, 0.f, 0.f};
#pragma unroll
        for (int kc = 0; kc < 4; kc++)
#pragma unroll
            for (int nf = 0; nf < 4; nf++) {
                bf16x8 kf = *(const bf16x8*)&K_lds[(nf * 16 + lx) * KST + kc * 32 + quad * 8];
                s[nf] = __builtin_amdgcn_mfma_f32_16x16x32_bf16(qf[kc], kf, s[nf], 0, 0, 0);
            }

        float p[4][4];
#pragma unroll
        for (int nf = 0; nf < 4; nf++)
#pragma unroll
            for (int r = 0; r < 4; r++) p[nf][r] = s[nf][r];

        // causal mask: only the diagonal tile (wave-uniform branch)
        if (st0 + it == jt) {
            int rowg = q0 + wave * 16 + quad * 4;
#pragma unroll
            for (int nf = 0; nf < 4; nf++) {
                int colg = s0 + nf * 16 + lx;
#pragma unroll
                for (int r = 0; r < 4; r++)
                    if (colg > rowg + r) p[nf][r] = -INFINITY;
            }
        }

        // row max across nf then 16 lanes
        float rm[4];
#pragma unroll
        for (int r = 0; r < 4; r++)
            rm[r] = fmaxf(fmaxf(p[0][r], p[1][r]), fmaxf(p[2][r], p[3][r]));
#pragma unroll
        for (int off = 1; off < 16; off <<= 1)
#pragma unroll
            for (int r = 0; r < 4; r++)
                rm[r] = fmaxf(rm[r], __shfl_xor(rm[r], off, 64));

        float alpha[4];
#pragma unroll
        for (int r = 0; r < 4; r++) {
            float mn = fmaxf(m_i[r], rm[r]);
            alpha[r] = exp2f(m_i[r] - mn);
            m_i[r]   = mn;
#pragma unroll
            for (int nf = 0; nf < 4; nf++)
                p[nf][r] = exp2f(p[nf][r] - mn);
        }
#pragma unroll
        for (int i = 0; i < 9; i++)
#pragma unroll
            for (int r = 0; r < 4; r++) o[i][r] *= alpha[r];

        // P (C-layout) -> LDS, pair-packed b32 writes from even lanes
#pragma unroll
        for (int nf = 0; nf < 4; nf++)
#pragma unroll
            for (int r = 0; r < 4; r++) {
                uint32_t u  = __float_as_uint(p[nf][r]) + 0x8000u;
                uint32_t pu = (uint32_t)__shfl_xor((int)u, 1, 64);
                uint32_t pk = __builtin_amdgcn_perm(pu, u, 0x07060302);
                if ((lane & 1) == 0)
                    *(uint32_t*)&P_lds[wave][(quad * 4 + r) * VST + nf * 16 + lx] = pk;
            }

        bf16x8 pf[2];
        pf[0] = *(const bf16x8*)&P_lds[wave][lx * VST + quad * 8];
        pf[1] = *(const bf16x8*)&P_lds[wave][lx * VST + 32 + quad * 8];
#pragma unroll
        for (int nf = 0; nf < 9; nf++)
#pragma unroll
            for (int kc = 0; kc < 2; kc++) {
                bf16x8 vf = *(const bf16x8*)&V_lds[(nf * 16 + lx) * VST + kc * 32 + quad * 8];
                o[nf] = __builtin_amdgcn_mfma_f32_16x16x32_bf16(pf[kc], vf, o[nf], 0, 0, 0);
            }
        __syncthreads();
    }

    // write unnormalized partial + (m, l) at the LOGICAL index
    float* pp = part + (size_t)lidx * (64 * 128);
#pragma unroll
    for (int nf = 0; nf < 8; nf++)
#pragma unroll
        for (int r = 0; r < 4; r++) {
            int lrow = wave * 16 + quad * 4 + r;
            pp[lrow * 128 + nf * 16 + lx] = o[nf][r];
        }
    if (lx == 0) {
#pragma unroll
        for (int r = 0; r < 4; r++) {
            int lrow = wave * 16 + quad * 4 + r;
            ml[(size_t)lidx * 128 + lrow * 2]     = m_i[r];
            ml[(size_t)lidx * 128 + lrow * 2 + 1] = o[8][r];  // l from ones-column MFMA
        }
    }
}

// ---------------------------------------------------------------------------
// Kernel 4: combine split-K partials (m values are in log2 domain).
// ---------------------------------------------------------------------------
__global__ __launch_bounds__(256) void combine(const float* __restrict__ part,
                                               const float* __restrict__ ml,
                                               float* __restrict__ out) {
    int bidx  = blockIdx.x;
    int batch = bidx >> 6;
    int jt    = bidx & 63;
    int g     = jt >> 3;
    int base  = batch * NCHUNK_PB + jt + g * (jt - 4 * g - 4);
    int nch   = g + 1;

    int tid  = threadIdx.x;
    int lrow = tid >> 2;
    int c0   = (tid & 3) * 32;

    float M = -INFINITY;
    for (int c = 0; c < nch; c++)
        M = fmaxf(M, ml[(size_t)(base + c) * 128 + lrow * 2]);

    float Lsum = 0.f;
    f32x4 acc[8];
#pragma unroll
    for (int i = 0; i < 8; i++) acc[i] = (f32x4){0.f, 0.f, 0.f, 0.f};

    for (int c = 0; c < nch; c++) {
        float m = ml[(size_t)(base + c) * 128 + lrow * 2];
        float l = ml[(size_t)(base + c) * 128 + lrow * 2 + 1];
        float w = exp2f(m - M);
        Lsum += l * w;
        const float* p = part + (size_t)(base + c) * (64 * 128) + lrow * 128 + c0;
#pragma unroll
        for (int i = 0; i < 8; i++) {
            f32x4 v = *(const f32x4*)(p + i * 4);
            acc[i] += v * w;
        }
    }
    float inv = 1.f / Lsum;
    size_t row = (size_t)(batch * T_ + jt * 64 + lrow);
#pragma unroll
    for (int i = 0; i < 8; i++)
        *(f32x4*)(out + row * 128 + c0 + i * 4) = acc[i] * inv;
}

// ---------------------------------------------------------------------------
extern "C" void kernel_launch(void* const* d_in, const int* in_sizes, int n_in,
                              void* d_out, int out_size, void* d_ws, size_t ws_size,
                              hipStream_t stream) {
    const float* x  = (const float*)d_in[0];
    const float* Wq = (const float*)d_in[1];
    const float* Wk = (const float*)d_in[2];
    const float* Wv = (const float*)d_in[3];
    float* out = (float*)d_out;

    uint16_t* ws = (uint16_t*)d_ws;
    uint16_t* qb = ws;                                   // 16384*128 bf16
    uint16_t* kb = qb + (size_t)16384 * 128;
    uint16_t* vT = kb + (size_t)16384 * 128;
    uint16_t* WT = vT + (size_t)16384 * 128;             // 3*128*1024
    float* part = (float*)(WT + (size_t)3 * D_ * C_);    // 1152*64*128 fp32
    float* ml   = part + (size_t)4 * NCHUNK_PB * 64 * 128;  // 1152*64*2 fp32

    prep_w<<<dim3((3 * D_ * C_ + 255) / 256), dim3(256), 0, stream>>>(Wq, Wk, Wv, WT);
    qkv_gemm<<<dim3(3 * (16384 / 64)), dim3(256), 0, stream>>>(x, WT, qb, kb, vT);
    attn<<<dim3(B_ * NCHUNK_PB), dim3(256), 0, stream>>>(qb, kb, vT, part, ml);
    combine<<<dim3(B_ * (T_ / 64)), dim3(256), 0, stream>>>(part, ml, out);
}